// Round 14
// baseline (100.805 us; speedup 1.0000x reference)
//
#include <hip/hip_runtime.h>
#include <cstdint>
#include <cstddef>

// MixedAttention: prep(both W transposes) -> MFMA qkv GEMM (f32->bf16, Q prescaled)
// -> {tile-MFMA na attn | MFMA flash self attn} -> MFMA proj GEMM with fused
// split-K combine in A-staging. 5 dispatches (was 7). po/pml in ws.

#define DIMC 512
#define HEADS 8
#define HD 32
#define KSZ 7
#define HH 48
#define WW 48
#define BB 2
#define NPIX (HH * WW)         // 2304
#define ROWS (BB * NPIX)       // 4608
#define C3 (3 * DIMC)          // 1536
#define TK 64                  // flash key tile
#define KSPLIT 4
#define KCHUNK (NPIX / KSPLIT) // 576
#define NTILES (KCHUNK / TK)   // 9
#define QB 128                 // queries per block (32 per wave)
#define NQBLK (NPIX / QB)      // 18
#define ROWE 40                // K LDS row stride bf16 (80B)
#define VSTR 72                // flash Vt row stride bf16
#define VROWE 232              // na Vt row stride
#define LOG2E 1.4426950408889634f

typedef __attribute__((ext_vector_type(8))) short short8;
typedef __attribute__((ext_vector_type(4))) float f32x4;
union frag8 { short8 s; uint32_t u[4]; };

static __device__ __forceinline__ float bf2f(uint32_t u) {
    return __builtin_bit_cast(float, u << 16);
}
static __device__ __forceinline__ uint16_t f2bf(float f) {
    uint32_t x = __builtin_bit_cast(uint32_t, f);
    uint32_t r = x + 0x7fffu + ((x >> 16) & 1u);
    return (uint16_t)(r >> 16);
}
static __device__ __forceinline__ uint32_t cvtpk(float lo, float hi) {
    uint32_t r;
    asm("v_cvt_pk_bf16_f32 %0, %1, %2" : "=v"(r) : "v"(lo), "v"(hi));
    return r;
}
static __device__ __forceinline__ float ex2(float x) {
    return __builtin_amdgcn_exp2f(x);
}

// ---------------- Both weight transposes in ONE dispatch.
// blocks [0,768): Wqkv (16 k-tiles x 48 n-tiles); [768,1024): Wproj (16x16).
__global__ __launch_bounds__(256)
void prep_weights(const float* __restrict__ Wqkv, const float* __restrict__ Wproj,
                  uint16_t* __restrict__ wqt, uint16_t* __restrict__ wpt)
{
    __shared__ float tile[32][33];
    int bid = blockIdx.x;
    const float* W; uint16_t* Wt; int N;
    if (bid < 768) { W = Wqkv; Wt = wqt; N = C3; }
    else { bid -= 768; W = Wproj; Wt = wpt; N = DIMC; }
    const int kt = bid & 15, nt = bid >> 4;
    const int K = DIMC;
    const int tx = threadIdx.x & 31, ty = threadIdx.x >> 5;
    const int k0 = kt * 32, n0 = nt * 32;
    #pragma unroll
    for (int i = 0; i < 4; ++i)
        tile[ty + 8 * i][tx] = W[(size_t)(k0 + ty + 8 * i) * N + n0 + tx];
    __syncthreads();
    #pragma unroll
    for (int i = 0; i < 4; ++i)
        Wt[(size_t)(n0 + ty + 8 * i) * K + k0 + tx] = f2bf(tile[tx][ty + 8 * i]);
}

// ---------------- MFMA GEMM. COMBINE: A cols [0,256) from attn_na (stride 256),
// cols [256,512) merged from split-K partials po/pml during staging (gemm2).
template<bool A_F32, bool OUT_F32, bool QSCALE, bool COMBINE>
__global__ __launch_bounds__(256)
void gemm_mfma(const void* __restrict__ Av, const uint16_t* __restrict__ Bt,
               const float* __restrict__ bias, void* __restrict__ Cv,
               int M, int N, int K,
               const uint16_t* __restrict__ po, const float2* __restrict__ pml)
{
    constexpr int BM = 128, BK = 32;
    constexpr float QSC = 0.17677669529663687f * LOG2E;
    __shared__ __align__(16) uint16_t Al[BM * ROWE];
    __shared__ __align__(16) uint16_t Bl[BM * ROWE];
    const int tid = threadIdx.x;
    const int lane = tid & 63, wv = tid >> 6;
    const int c = lane & 15, g = lane >> 4;
    const int wr = wv >> 1, wc = wv & 1;
    const int m0 = blockIdx.y * BM, n0 = blockIdx.x * BM;
    const int srow = tid >> 2, skc = (tid & 3) * 8;

    f32x4 acc[4][4];
    #pragma unroll
    for (int mi = 0; mi < 4; ++mi)
        #pragma unroll
        for (int ni = 0; ni < 4; ++ni)
            acc[mi][ni] = (f32x4){0.f, 0.f, 0.f, 0.f};

    for (int k0 = 0; k0 < K; k0 += BK) {
        __syncthreads();
        #pragma unroll
        for (int half = 0; half < 2; ++half) {
            const int row = srow + half * 64;
            if (COMBINE) {
                const int col0 = k0 + skc;          // wave-uniform side of 256
                const int rglob = m0 + row;
                if (col0 < 256) {
                    *reinterpret_cast<uint4*>(&Al[row * ROWE + skc]) =
                        *reinterpret_cast<const uint4*>(
                            &((const uint16_t*)Av)[(size_t)rglob * 256 + col0]);
                } else {
                    const int cs = col0 - 256;
                    const int hh = cs >> 5, d0 = cs & 31;
                    const int bb_ = (rglob >= NPIX) ? 1 : 0;
                    const int q = rglob - bb_ * NPIX;
                    const size_t base = (size_t)(bb_ * 8 + hh) * NPIX + q;
                    float2 ml[KSPLIT];
                    float M2 = -1e30f;
                    #pragma unroll
                    for (int s = 0; s < KSPLIT; ++s) {
                        ml[s] = pml[(size_t)s * 16 * NPIX + base];
                        M2 = fmaxf(M2, ml[s].x);
                    }
                    float w[KSPLIT], den = 0.f;
                    #pragma unroll
                    for (int s = 0; s < KSPLIT; ++s) {
                        w[s] = ex2(ml[s].x - M2) * ml[s].y;
                        den += w[s];
                    }
                    const float inv = 1.f / den;
                    uint4 pv[KSPLIT];
                    #pragma unroll
                    for (int s = 0; s < KSPLIT; ++s)
                        pv[s] = *reinterpret_cast<const uint4*>(
                            &po[((size_t)s * 16 * NPIX + base) * HD + d0]);
                    uint32_t outw[4];
                    #pragma unroll
                    for (int jp = 0; jp < 4; ++jp) {
                        float nlo = 0.f, nhi = 0.f;
                        #pragma unroll
                        for (int s = 0; s < KSPLIT; ++s) {
                            const uint32_t wd = (&pv[s].x)[jp];
                            nlo = fmaf(w[s], bf2f(wd & 0xffffu), nlo);
                            nhi = fmaf(w[s], bf2f(wd >> 16), nhi);
                        }
                        outw[jp] = cvtpk(nlo * inv, nhi * inv);
                    }
                    *reinterpret_cast<uint4*>(&Al[row * ROWE + skc]) =
                        make_uint4(outw[0], outw[1], outw[2], outw[3]);
                }
            } else if (A_F32) {
                const float* A32 = (const float*)Av;
                const float4 a0 = *reinterpret_cast<const float4*>(&A32[(size_t)(m0 + row) * K + k0 + skc]);
                const float4 a1 = *reinterpret_cast<const float4*>(&A32[(size_t)(m0 + row) * K + k0 + skc + 4]);
                *reinterpret_cast<uint4*>(&Al[row * ROWE + skc]) =
                    make_uint4(cvtpk(a0.x, a0.y), cvtpk(a0.z, a0.w),
                               cvtpk(a1.x, a1.y), cvtpk(a1.z, a1.w));
            } else {
                const uint16_t* A16 = (const uint16_t*)Av;
                *reinterpret_cast<uint4*>(&Al[row * ROWE + skc]) =
                    *reinterpret_cast<const uint4*>(&A16[(size_t)(m0 + row) * K + k0 + skc]);
            }
            *reinterpret_cast<uint4*>(&Bl[row * ROWE + skc]) =
                *reinterpret_cast<const uint4*>(&Bt[(size_t)(n0 + row) * K + k0 + skc]);
        }
        __syncthreads();

        frag8 a[4], b[4];
        #pragma unroll
        for (int mi = 0; mi < 4; ++mi)
            a[mi].s = *reinterpret_cast<const short8*>(&Al[(wr * 64 + mi * 16 + c) * ROWE + g * 8]);
        #pragma unroll
        for (int ni = 0; ni < 4; ++ni)
            b[ni].s = *reinterpret_cast<const short8*>(&Bl[(wc * 64 + ni * 16 + c) * ROWE + g * 8]);
        #pragma unroll
        for (int mi = 0; mi < 4; ++mi)
            #pragma unroll
            for (int ni = 0; ni < 4; ++ni)
                acc[mi][ni] = __builtin_amdgcn_mfma_f32_16x16x32_bf16(
                    a[mi].s, b[ni].s, acc[mi][ni], 0, 0, 0);
    }

    #pragma unroll
    for (int mi = 0; mi < 4; ++mi) {
        #pragma unroll
        for (int ni = 0; ni < 4; ++ni) {
            const int row = m0 + wr * 64 + mi * 16 + 4 * g;
            const int col = n0 + wc * 64 + ni * 16 + c;
            const float bv = bias[col];
            float f = 1.f;
            if (QSCALE) f = (col < 256 || (col >= 768 && col < 1024)) ? QSC : 1.f;
            #pragma unroll
            for (int r = 0; r < 4; ++r) {
                const float val = (acc[mi][ni][r] + bv) * f;
                if (OUT_F32)
                    ((float*)Cv)[(size_t)(row + r) * N + col] = val;
                else
                    ((uint16_t*)Cv)[(size_t)(row + r) * N + col] = f2bf(val);
            }
        }
    }
}

// ---------------- Tile-MFMA neighborhood attention -> attn_na[ROWS][256]
__global__ __launch_bounds__(256)
void na_attn_mfma(const uint16_t* __restrict__ qkv, const float* __restrict__ rpb,
                  uint16_t* __restrict__ attn_na)
{
    const int tid = threadIdx.x;
    const int lane = tid & 63, wv = tid >> 6;
    const int c = lane & 15, g = lane >> 4, g4 = g * 4;
    const int bid = blockIdx.x;
    const int tile = bid % 36;
    const int bh = bid / 36;
    const int h = bh & (HEADS - 1), b = bh >> 3;
    const int t0i = (tile / 6) * 8, t0j = (tile % 6) * 8;
    const int u0i = min(max(t0i - 3, 0), HH - 14);
    const int u0j = min(max(t0j - 3, 0), WW - 14);
    const size_t rowbase = (size_t)b * NPIX;

    __shared__ __align__(16) uint16_t K_l[224 * ROWE];
    __shared__ __align__(16) uint16_t Vt[32 * VROWE];
    __shared__ float rpb_l[169];

    if (tid < 169) rpb_l[tid] = rpb[h * 169 + tid] * LOG2E;
    #pragma unroll
    for (int it = 0; it < 4; ++it) {
        const int idx = it * 256 + tid;
        if (idx < 896) {
            const int u = idx >> 2, dc = idx & 3;
            const int uc = u & 15, ur = u >> 4;
            if (uc < 14) {
                const int grow = (u0i + ur) * WW + (u0j + uc);
                const uint16_t* src = qkv + (rowbase + grow) * C3 + 256 + h * HD + dc * 8;
                *reinterpret_cast<uint4*>(&K_l[u * ROWE + dc * 8]) =
                    *reinterpret_cast<const uint4*>(src);
                const uint4 vw = *reinterpret_cast<const uint4*>(src + 256);
                const uint16_t* vh = reinterpret_cast<const uint16_t*>(&vw);
                #pragma unroll
                for (int i = 0; i < 8; ++i)
                    Vt[(dc * 8 + i) * VROWE + u] = vh[i];
            } else {
                *reinterpret_cast<uint4*>(&K_l[u * ROWE + dc * 8]) = make_uint4(0, 0, 0, 0);
                #pragma unroll
                for (int i = 0; i < 8; ++i)
                    Vt[(dc * 8 + i) * VROWE + u] = 0;
            }
        }
    }

    const int qid = wv * 16 + c;
    const int qi = t0i + (qid >> 3), qj = t0j + (qid & 7);
    const int pixq = qi * WW + qj;
    const int niq = min(max(qi - 3, 0), HH - KSZ);
    const int njq = min(max(qj - 3, 0), WW - KSZ);
    const int piq = 3 + max(3 - qi, 0) + ((qi + 3 >= HH) ? (HH - qi - 4) : 0);
    const int pjq = 3 + max(3 - qj, 0) + ((qj + 3 >= WW) ? (WW - qj - 4) : 0);
    const int ni_rel = niq - u0i, nj_rel = njq - u0j;
    const int bb = (piq - ni_rel) * 13 + (pjq - nj_rel);

    frag8 qf;
    qf.s = *reinterpret_cast<const short8*>(qkv + (rowbase + pixq) * C3 + h * HD + g * 8);

    __syncthreads();

    float pex[14][4];
    float m = -1e30f;
    #pragma unroll
    for (int f = 0; f < 14; ++f) {
        frag8 ka;
        ka.s = *reinterpret_cast<const short8*>(&K_l[(16 * f + c) * ROWE + g * 8]);
        f32x4 s = {0.f, 0.f, 0.f, 0.f};
        s = __builtin_amdgcn_mfma_f32_16x16x32_bf16(ka.s, qf.s, s, 0, 0, 0);
        const bool rok = (unsigned)(f - ni_rel) < 7u;
        #pragma unroll
        for (int r = 0; r < 4; ++r) {
            const int uc = g4 + r;
            const bool ok = rok && ((unsigned)(uc - nj_rel) < 7u);
            const int addr = ok ? (bb + 13 * f + uc) : 0;
            const float v = s[r] + rpb_l[addr];
            pex[f][r] = ok ? v : -1e30f;
            m = fmaxf(m, pex[f][r]);
        }
    }
    m = fmaxf(m, __shfl_xor(m, 16));
    m = fmaxf(m, __shfl_xor(m, 32));
    float l = 0.f;
    #pragma unroll
    for (int f = 0; f < 14; ++f)
        #pragma unroll
        for (int r = 0; r < 4; ++r) {
            pex[f][r] = ex2(pex[f][r] - m);
            l += pex[f][r];
        }
    l += __shfl_xor(l, 16);
    l += __shfl_xor(l, 32);

    f32x4 of0 = {0.f, 0.f, 0.f, 0.f}, of1 = {0.f, 0.f, 0.f, 0.f};
    const int sbase = (g & 1) * 32 + c;
    #pragma unroll
    for (int kk = 0; kk < 7; ++kk) {
        uint32_t pk0[2], pk1[2];
        pk0[0] = cvtpk(pex[2 * kk][0], pex[2 * kk][1]);
        pk0[1] = cvtpk(pex[2 * kk][2], pex[2 * kk][3]);
        pk1[0] = cvtpk(pex[2 * kk + 1][0], pex[2 * kk + 1][1]);
        pk1[1] = cvtpk(pex[2 * kk + 1][2], pex[2 * kk + 1][3]);
        frag8 pb;
        #pragma unroll
        for (int tt = 0; tt < 4; ++tt) {
            const int srcLane = sbase + ((tt >> 1) << 4);
            const uint32_t v0 = __shfl(pk0[tt & 1], srcLane);
            const uint32_t v1 = __shfl(pk1[tt & 1], srcLane);
            pb.u[tt] = (g >= 2) ? v1 : v0;
        }
        frag8 va0, va1;
        va0.s = *reinterpret_cast<const short8*>(&Vt[c * VROWE + kk * 32 + g * 8]);
        va1.s = *reinterpret_cast<const short8*>(&Vt[(16 + c) * VROWE + kk * 32 + g * 8]);
        of0 = __builtin_amdgcn_mfma_f32_16x16x32_bf16(va0.s, pb.s, of0, 0, 0, 0);
        of1 = __builtin_amdgcn_mfma_f32_16x16x32_bf16(va1.s, pb.s, of1, 0, 0, 0);
    }

    const float invl = 1.f / l;
    uint32_t* dst = reinterpret_cast<uint32_t*>(attn_na + (rowbase + pixq) * 256 + h * HD);
    dst[2 * g + 0] = cvtpk(of0[0] * invl, of0[1] * invl);
    dst[2 * g + 1] = cvtpk(of0[2] * invl, of0[3] * invl);
    dst[8 + 2 * g + 0] = cvtpk(of1[0] * invl, of1[1] * invl);
    dst[8 + 2 * g + 1] = cvtpk(of1[2] * invl, of1[3] * invl);
}

// ---------------- MFMA flash self-attention v6 (unchanged from r13; po in ws)
__global__ __launch_bounds__(256)
void self_attn_flash(const uint16_t* __restrict__ qkv,
                     uint16_t* __restrict__ po, float2* __restrict__ pml)
{
    const int tid = threadIdx.x;
    const int lane = tid & 63, wv = tid >> 6;
    const int c = lane & 15, g = lane >> 4;
    const int bid = blockIdx.x;               // [bh][qblk][split]
    const int split = bid & (KSPLIT - 1);
    const int qblk = (bid >> 2) % NQBLK;
    const int bh = bid / (KSPLIT * NQBLK);
    const int h = bh & (HEADS - 1);
    const int b = bh >> 3;
    const size_t rowbase = (size_t)b * NPIX;
    const int qbase = qblk * QB + wv * 32;
    const int q0 = qbase + c, q1 = qbase + 16 + c;

    __shared__ __align__(16) uint16_t Ks[2][TK * ROWE];
    __shared__ __align__(16) uint16_t Vt[2][32 * VSTR];

    frag8 qf0, qf1;
    qf0.s = *reinterpret_cast<const short8*>(qkv + (rowbase + q0) * C3 + 768 + h * HD + g * 8);
    qf1.s = *reinterpret_cast<const short8*>(qkv + (rowbase + q1) * C3 + 768 + h * HD + g * 8);

    float m0 = -1e30f, m1 = -1e30f, ls0 = 0.f, ls1 = 0.f;
    f32x4 oa00 = {0,0,0,0}, oa01 = {0,0,0,0};
    f32x4 oa10 = {0,0,0,0}, oa11 = {0,0,0,0};

    const int skk = tid >> 2, kd = (tid & 3) * 8;
    const int sgk = (skk & 15) | ((skk & 16) << 1) | ((skk & 32) >> 1);
    const int skv = tid >> 3, sdc = tid & 7;
    const int cp2 = 2 * (skv ^ ((sdc >> 1) << 3));

    uint4 KW; uint2 VA, VB;
#define STAGE_LOAD(T) do {                                                            \
    const size_t _tb = rowbase + split * KCHUNK + (T) * TK;                           \
    KW = *reinterpret_cast<const uint4*>(qkv + (_tb + sgk) * C3 + 1024 + h * HD + kd);\
    const uint16_t* _vp = qkv + (_tb + skv) * C3 + 1280 + h * HD + sdc * 4;           \
    VA = *reinterpret_cast<const uint2*>(_vp);                                        \
    VB = *reinterpret_cast<const uint2*>(_vp + 32 * C3); } while (0)

#define STAGE_WRITE(BUF) do {                                                         \
    *reinterpret_cast<uint4*>(&Ks[BUF][skk * ROWE + kd]) = KW;                        \
    const uint32_t _pa[4] = {VA.x & 0xffffu, VA.x >> 16, VA.y & 0xffffu, VA.y >> 16}; \
    const uint32_t _pb[4] = {VB.x & 0xffffu, VB.x >> 16, VB.y & 0xffffu, VB.y >> 16}; \
    _Pragma("unroll")                                                                 \
    for (int _i = 0; _i < 4; ++_i)                                                    \
        *reinterpret_cast<uint32_t*>(&Vt[BUF][(sdc * 4 + _i) * VSTR + cp2]) =         \
            _pa[_i] | (_pb[_i] << 16); } while (0)

    STAGE_LOAD(0);
    STAGE_WRITE(0);

    const int x0 = (c >> 3) << 3;
    const int x1 = 16 + x0;

    for (int t = 0; t < NTILES; ++t) {
        __syncthreads();

        const bool more = (t + 1 < NTILES);
        if (more) STAGE_LOAD(t + 1);

        const int cur = t & 1;
        frag8 ka0, ka1, ka2, ka3;
        ka0.s = *reinterpret_cast<const short8*>(&Ks[cur][c * ROWE + g * 8]);
        ka1.s = *reinterpret_cast<const short8*>(&Ks[cur][(16 + c) * ROWE + g * 8]);
        ka2.s = *reinterpret_cast<const short8*>(&Ks[cur][(32 + c) * ROWE + g * 8]);
        ka3.s = *reinterpret_cast<const short8*>(&Ks[cur][(48 + c) * ROWE + g * 8]);
        f32x4 sc0[4], sc1[4];
        #pragma unroll
        for (int kf = 0; kf < 4; ++kf) {
            sc0[kf] = (f32x4){0,0,0,0};
            sc1[kf] = (f32x4){0,0,0,0};
        }
        __builtin_amdgcn_s_setprio(1);
        sc0[0] = __builtin_amdgcn_mfma_f32_16x16x32_bf16(ka0.s, qf0.s, sc0[0], 0, 0, 0);
        sc0[1] = __builtin_amdgcn_mfma_f32_16x16x32_bf16(ka1.s, qf0.s, sc0[1], 0, 0, 0);
        sc0[2] = __builtin_amdgcn_mfma_f32_16x16x32_bf16(ka2.s, qf0.s, sc0[2], 0, 0, 0);
        sc0[3] = __builtin_amdgcn_mfma_f32_16x16x32_bf16(ka3.s, qf0.s, sc0[3], 0, 0, 0);
        sc1[0] = __builtin_amdgcn_mfma_f32_16x16x32_bf16(ka0.s, qf1.s, sc1[0], 0, 0, 0);
        sc1[1] = __builtin_amdgcn_mfma_f32_16x16x32_bf16(ka1.s, qf1.s, sc1[1], 0, 0, 0);
        sc1[2] = __builtin_amdgcn_mfma_f32_16x16x32_bf16(ka2.s, qf1.s, sc1[2], 0, 0, 0);
        sc1[3] = __builtin_amdgcn_mfma_f32_16x16x32_bf16(ka3.s, qf1.s, sc1[3], 0, 0, 0);
        __builtin_amdgcn_s_setprio(0);

        float t0 = sc0[0][0], t1 = sc1[0][0];
        #pragma unroll
        for (int kf = 0; kf < 4; ++kf)
            #pragma unroll
            for (int r = 0; r < 4; ++r) {
                t0 = fmaxf(t0, sc0[kf][r]);
                t1 = fmaxf(t1, sc1[kf][r]);
            }
        t0 = fmaxf(t0, __shfl_xor(t0, 16)); t0 = fmaxf(t0, __shfl_xor(t0, 32));
        t1 = fmaxf(t1, __shfl_xor(t1, 16)); t1 = fmaxf(t1, __shfl_xor(t1, 32));

        const int ok = (t0 - m0 <= 11.54f) && (t1 - m1 <= 11.54f);
        if (!__all(ok)) {
            const float nm0 = fmaxf(m0, t0), nm1 = fmaxf(m1, t1);
            const float c0 = ex2(m0 - nm0), c1 = ex2(m1 - nm1);
            ls0 *= c0; ls1 *= c1;
            oa00 *= c0; oa01 *= c0; oa10 *= c1; oa11 *= c1;
            m0 = nm0; m1 = nm1;
        }

        #pragma unroll
        for (int kf = 0; kf < 4; ++kf)
            #pragma unroll
            for (int r = 0; r < 4; ++r) {
                sc0[kf][r] = ex2(sc0[kf][r] - m0); ls0 += sc0[kf][r];
                sc1[kf][r] = ex2(sc1[kf][r] - m1); ls1 += sc1[kf][r];
            }

        #pragma unroll
        for (int kk = 0; kk < 2; ++kk) {
            frag8 pb0, pb1;
            #pragma unroll
            for (int tt = 0; tt < 4; ++tt) {
                pb0.u[tt] = cvtpk(sc0[2 * kk][tt], sc0[2 * kk + 1][tt]);
                pb1.u[tt] = cvtpk(sc1[2 * kk][tt], sc1[2 * kk + 1][tt]);
            }
            const int p0 = 16 * kk + 4 * g;
            frag8 va0, va1;
            va0.s = *reinterpret_cast<const short8*>(&Vt[cur][c * VSTR + 2 * (p0 ^ x0)]);
            va1.s = *reinterpret_cast<const short8*>(&Vt[cur][(16 + c) * VSTR + 2 * (p0 ^ x1)]);
            __builtin_amdgcn_s_setprio(1);
            oa00 = __builtin_amdgcn_mfma_f32_16x16x32_bf16(va0.s, pb0.s, oa00, 0, 0, 0);
            oa01 = __builtin_amdgcn_mfma_f32_16x16x32_bf16(va1.s, pb0.s, oa01, 0, 0, 0);
            oa10 = __builtin_amdgcn_mfma_f32_16x16x32_bf16(va0.s, pb1.s, oa10, 0, 0, 0);
            oa11 = __builtin_amdgcn_mfma_f32_16x16x32_bf16(va1.s, pb1.s, oa11, 0, 0, 0);
            __builtin_amdgcn_s_setprio(0);
        }

        if (more) STAGE_WRITE(cur ^ 1);
    }

    ls0 += __shfl_xor(ls0, 16); ls0 += __shfl_xor(ls0, 32);
    ls1 += __shfl_xor(ls1, 16); ls1 += __shfl_xor(ls1, 32);

    const float i0 = 1.f / ls0, i1 = 1.f / ls1;
    const size_t item0 = ((size_t)split * 16 + bh) * NPIX + q0;
    const size_t item1 = ((size_t)split * 16 + bh) * NPIX + q1;
    uint32_t* d0 = reinterpret_cast<uint32_t*>(po + item0 * HD);
    d0[2 * g + 0] = cvtpk(oa00[0] * i0, oa00[1] * i0);
    d0[2 * g + 1] = cvtpk(oa00[2] * i0, oa00[3] * i0);
    d0[8 + 2 * g + 0] = cvtpk(oa01[0] * i0, oa01[1] * i0);
    d0[8 + 2 * g + 1] = cvtpk(oa01[2] * i0, oa01[3] * i0);
    uint32_t* d1 = reinterpret_cast<uint32_t*>(po + item1 * HD);
    d1[2 * g + 0] = cvtpk(oa10[0] * i1, oa10[1] * i1);
    d1[2 * g + 1] = cvtpk(oa10[2] * i1, oa10[3] * i1);
    d1[8 + 2 * g + 0] = cvtpk(oa11[0] * i1, oa11[1] * i1);
    d1[8 + 2 * g + 1] = cvtpk(oa11[2] * i1, oa11[3] * i1);
    if (g == 0) {
        pml[item0] = make_float2(m0, ls0);
        pml[item1] = make_float2(m1, ls1);
    }
#undef STAGE_LOAD
#undef STAGE_WRITE
}

extern "C" void kernel_launch(void* const* d_in, const int* in_sizes, int n_in,
                              void* d_out, int out_size, void* d_ws, size_t ws_size,
                              hipStream_t stream)
{
    const float* x     = (const float*)d_in[0];
    const float* Wqkv  = (const float*)d_in[1];
    const float* bqkv  = (const float*)d_in[2];
    const float* rpb   = (const float*)d_in[3];
    const float* Wproj = (const float*)d_in[4];
    const float* bproj = (const float*)d_in[5];

    uint16_t* qkv     = (uint16_t*)d_ws;                          // 14.2 MB
    uint16_t* attn_na = qkv + (size_t)ROWS * C3;                  //  2.4 MB
    uint16_t* wqt     = attn_na + (size_t)ROWS * 256;             //  1.6 MB
    uint16_t* wpt     = wqt + (size_t)C3 * DIMC;                  //  0.5 MB
    uint16_t* po      = wpt + (size_t)DIMC * DIMC;                //  9.4 MB
    float2*   pml     = (float2*)(po + (size_t)KSPLIT * 16 * NPIX * HD); // 1.2 MB (8B-aligned)

    const dim3 blk(256);
    prep_weights<<<dim3(1024), blk, 0, stream>>>(Wqkv, Wproj, wqt, wpt);
    gemm_mfma<true, false, true, false><<<dim3(C3 / 128, ROWS / 128), blk, 0, stream>>>(
        x, wqt, bqkv, qkv, ROWS, C3, DIMC, nullptr, nullptr);
    na_attn_mfma<<<dim3(BB * HEADS * 36), blk, 0, stream>>>(qkv, rpb, attn_na);
    self_attn_flash<<<dim3(16 * NQBLK * KSPLIT), blk, 0, stream>>>(qkv, po, pml);
    gemm_mfma<false, true, false, true><<<dim3(DIMC / 128, ROWS / 128), blk, 0, stream>>>(
        attn_na, wpt, bproj, d_out, ROWS, DIMC, DIMC, po, pml);
}

// Round 15
// 81.900 us; speedup vs baseline: 1.2308x; 1.2308x over previous
//
#include <hip/hip_runtime.h>
#include <cstdint>
#include <cstddef>

// MixedAttention r15: prep(W transposes, 1 dispatch) -> MFMA qkv GEMM ->
// attn_fused{1152 flash blocks + 576 na blocks, one dispatch} -> combine ->
// MFMA proj GEMM. 5 dispatches. r14's in-GEMM combine reverted (4x redundant).

#define DIMC 512
#define HEADS 8
#define HD 32
#define KSZ 7
#define HH 48
#define WW 48
#define BB 2
#define NPIX (HH * WW)         // 2304
#define ROWS (BB * NPIX)       // 4608
#define C3 (3 * DIMC)          // 1536
#define TK 64                  // flash key tile
#define KSPLIT 4
#define KCHUNK (NPIX / KSPLIT) // 576
#define NTILES (KCHUNK / TK)   // 9
#define QB 128                 // queries per block (32 per wave)
#define NQBLK (NPIX / QB)      // 18
#define NFLASH (16 * NQBLK * KSPLIT)  // 1152
#define ROWE 40                // K LDS row stride bf16 (80B)
#define VSTR 72                // flash Vt row stride bf16
#define VROWE 232              // na Vt row stride
#define LOG2E 1.4426950408889634f

typedef __attribute__((ext_vector_type(8))) short short8;
typedef __attribute__((ext_vector_type(4))) float f32x4;
union frag8 { short8 s; uint32_t u[4]; };

static __device__ __forceinline__ float bf2f(uint32_t u) {
    return __builtin_bit_cast(float, u << 16);
}
static __device__ __forceinline__ uint16_t f2bf(float f) {
    uint32_t x = __builtin_bit_cast(uint32_t, f);
    uint32_t r = x + 0x7fffu + ((x >> 16) & 1u);
    return (uint16_t)(r >> 16);
}
static __device__ __forceinline__ uint32_t cvtpk(float lo, float hi) {
    uint32_t r;
    asm("v_cvt_pk_bf16_f32 %0, %1, %2" : "=v"(r) : "v"(lo), "v"(hi));
    return r;
}
static __device__ __forceinline__ float ex2(float x) {
    return __builtin_amdgcn_exp2f(x);
}

// ---------------- Both weight transposes in ONE dispatch (r14, kept).
__global__ __launch_bounds__(256)
void prep_weights(const float* __restrict__ Wqkv, const float* __restrict__ Wproj,
                  uint16_t* __restrict__ wqt, uint16_t* __restrict__ wpt)
{
    __shared__ float tile[32][33];
    int bid = blockIdx.x;
    const float* W; uint16_t* Wt; int N;
    if (bid < 768) { W = Wqkv; Wt = wqt; N = C3; }
    else { bid -= 768; W = Wproj; Wt = wpt; N = DIMC; }
    const int kt = bid & 15, nt = bid >> 4;
    const int K = DIMC;
    const int tx = threadIdx.x & 31, ty = threadIdx.x >> 5;
    const int k0 = kt * 32, n0 = nt * 32;
    #pragma unroll
    for (int i = 0; i < 4; ++i)
        tile[ty + 8 * i][tx] = W[(size_t)(k0 + ty + 8 * i) * N + n0 + tx];
    __syncthreads();
    #pragma unroll
    for (int i = 0; i < 4; ++i)
        Wt[(size_t)(n0 + ty + 8 * i) * K + k0 + tx] = f2bf(tile[tx][ty + 8 * i]);
}

// ---------------- MFMA GEMM (r13 version): C = A * Bt^T + bias
template<bool A_F32, bool OUT_F32, bool QSCALE>
__global__ __launch_bounds__(256)
void gemm_mfma(const void* __restrict__ Av, const uint16_t* __restrict__ Bt,
               const float* __restrict__ bias, void* __restrict__ Cv,
               int M, int N, int K)
{
    constexpr int BM = 128, BK = 32;
    constexpr float QSC = 0.17677669529663687f * LOG2E;
    __shared__ __align__(16) uint16_t Al[BM * ROWE];
    __shared__ __align__(16) uint16_t Bl[BM * ROWE];
    const int tid = threadIdx.x;
    const int lane = tid & 63, wv = tid >> 6;
    const int c = lane & 15, g = lane >> 4;
    const int wr = wv >> 1, wc = wv & 1;
    const int m0 = blockIdx.y * BM, n0 = blockIdx.x * BM;
    const int srow = tid >> 2, skc = (tid & 3) * 8;

    f32x4 acc[4][4];
    #pragma unroll
    for (int mi = 0; mi < 4; ++mi)
        #pragma unroll
        for (int ni = 0; ni < 4; ++ni)
            acc[mi][ni] = (f32x4){0.f, 0.f, 0.f, 0.f};

    for (int k0 = 0; k0 < K; k0 += BK) {
        __syncthreads();
        #pragma unroll
        for (int half = 0; half < 2; ++half) {
            const int row = srow + half * 64;
            if (A_F32) {
                const float* A32 = (const float*)Av;
                const float4 a0 = *reinterpret_cast<const float4*>(&A32[(size_t)(m0 + row) * K + k0 + skc]);
                const float4 a1 = *reinterpret_cast<const float4*>(&A32[(size_t)(m0 + row) * K + k0 + skc + 4]);
                *reinterpret_cast<uint4*>(&Al[row * ROWE + skc]) =
                    make_uint4(cvtpk(a0.x, a0.y), cvtpk(a0.z, a0.w),
                               cvtpk(a1.x, a1.y), cvtpk(a1.z, a1.w));
            } else {
                const uint16_t* A16 = (const uint16_t*)Av;
                *reinterpret_cast<uint4*>(&Al[row * ROWE + skc]) =
                    *reinterpret_cast<const uint4*>(&A16[(size_t)(m0 + row) * K + k0 + skc]);
            }
            *reinterpret_cast<uint4*>(&Bl[row * ROWE + skc]) =
                *reinterpret_cast<const uint4*>(&Bt[(size_t)(n0 + row) * K + k0 + skc]);
        }
        __syncthreads();

        frag8 a[4], b[4];
        #pragma unroll
        for (int mi = 0; mi < 4; ++mi)
            a[mi].s = *reinterpret_cast<const short8*>(&Al[(wr * 64 + mi * 16 + c) * ROWE + g * 8]);
        #pragma unroll
        for (int ni = 0; ni < 4; ++ni)
            b[ni].s = *reinterpret_cast<const short8*>(&Bl[(wc * 64 + ni * 16 + c) * ROWE + g * 8]);
        #pragma unroll
        for (int mi = 0; mi < 4; ++mi)
            #pragma unroll
            for (int ni = 0; ni < 4; ++ni)
                acc[mi][ni] = __builtin_amdgcn_mfma_f32_16x16x32_bf16(
                    a[mi].s, b[ni].s, acc[mi][ni], 0, 0, 0);
    }

    #pragma unroll
    for (int mi = 0; mi < 4; ++mi) {
        #pragma unroll
        for (int ni = 0; ni < 4; ++ni) {
            const int row = m0 + wr * 64 + mi * 16 + 4 * g;
            const int col = n0 + wc * 64 + ni * 16 + c;
            const float bv = bias[col];
            float f = 1.f;
            if (QSCALE) f = (col < 256 || (col >= 768 && col < 1024)) ? QSC : 1.f;
            #pragma unroll
            for (int r = 0; r < 4; ++r) {
                const float val = (acc[mi][ni][r] + bv) * f;
                if (OUT_F32)
                    ((float*)Cv)[(size_t)(row + r) * N + col] = val;
                else
                    ((uint16_t*)Cv)[(size_t)(row + r) * N + col] = f2bf(val);
            }
        }
    }
}

// ---------------- na body (r13 logic, smem passed in) -> attn[:, h*32 .. ), stride DIMC
static __device__ __forceinline__
void na_body(uint8_t* smem, int bid, const uint16_t* __restrict__ qkv,
             const float* __restrict__ rpb, uint16_t* __restrict__ attn)
{
    uint16_t* K_l   = (uint16_t*)smem;                 // 224*40*2 = 17920 B
    uint16_t* Vt    = (uint16_t*)(smem + 17920);       // 32*232*2 = 14848 B
    float*    rpb_l = (float*)(smem + 32768);          // 676 B

    const int tid = threadIdx.x;
    const int lane = tid & 63, wv = tid >> 6;
    const int c = lane & 15, g = lane >> 4, g4 = g * 4;
    const int tile = bid % 36;
    const int bh = bid / 36;
    const int h = bh & (HEADS - 1), b = bh >> 3;
    const int t0i = (tile / 6) * 8, t0j = (tile % 6) * 8;
    const int u0i = min(max(t0i - 3, 0), HH - 14);
    const int u0j = min(max(t0j - 3, 0), WW - 14);
    const size_t rowbase = (size_t)b * NPIX;

    if (tid < 169) rpb_l[tid] = rpb[h * 169 + tid] * LOG2E;
    #pragma unroll
    for (int it = 0; it < 4; ++it) {
        const int idx = it * 256 + tid;
        if (idx < 896) {
            const int u = idx >> 2, dc = idx & 3;
            const int uc = u & 15, ur = u >> 4;
            if (uc < 14) {
                const int grow = (u0i + ur) * WW + (u0j + uc);
                const uint16_t* src = qkv + (rowbase + grow) * C3 + 256 + h * HD + dc * 8;
                *reinterpret_cast<uint4*>(&K_l[u * ROWE + dc * 8]) =
                    *reinterpret_cast<const uint4*>(src);
                const uint4 vw = *reinterpret_cast<const uint4*>(src + 256);
                const uint16_t* vh = reinterpret_cast<const uint16_t*>(&vw);
                #pragma unroll
                for (int i = 0; i < 8; ++i)
                    Vt[(dc * 8 + i) * VROWE + u] = vh[i];
            } else {
                *reinterpret_cast<uint4*>(&K_l[u * ROWE + dc * 8]) = make_uint4(0, 0, 0, 0);
                #pragma unroll
                for (int i = 0; i < 8; ++i)
                    Vt[(dc * 8 + i) * VROWE + u] = 0;
            }
        }
    }

    const int qid = wv * 16 + c;
    const int qi = t0i + (qid >> 3), qj = t0j + (qid & 7);
    const int pixq = qi * WW + qj;
    const int niq = min(max(qi - 3, 0), HH - KSZ);
    const int njq = min(max(qj - 3, 0), WW - KSZ);
    const int piq = 3 + max(3 - qi, 0) + ((qi + 3 >= HH) ? (HH - qi - 4) : 0);
    const int pjq = 3 + max(3 - qj, 0) + ((qj + 3 >= WW) ? (WW - qj - 4) : 0);
    const int ni_rel = niq - u0i, nj_rel = njq - u0j;
    const int bb = (piq - ni_rel) * 13 + (pjq - nj_rel);

    frag8 qf;
    qf.s = *reinterpret_cast<const short8*>(qkv + (rowbase + pixq) * C3 + h * HD + g * 8);

    __syncthreads();

    float pex[14][4];
    float m = -1e30f;
    #pragma unroll
    for (int f = 0; f < 14; ++f) {
        frag8 ka;
        ka.s = *reinterpret_cast<const short8*>(&K_l[(16 * f + c) * ROWE + g * 8]);
        f32x4 s = {0.f, 0.f, 0.f, 0.f};
        s = __builtin_amdgcn_mfma_f32_16x16x32_bf16(ka.s, qf.s, s, 0, 0, 0);
        const bool rok = (unsigned)(f - ni_rel) < 7u;
        #pragma unroll
        for (int r = 0; r < 4; ++r) {
            const int uc = g4 + r;
            const bool ok = rok && ((unsigned)(uc - nj_rel) < 7u);
            const int addr = ok ? (bb + 13 * f + uc) : 0;
            const float v = s[r] + rpb_l[addr];
            pex[f][r] = ok ? v : -1e30f;
            m = fmaxf(m, pex[f][r]);
        }
    }
    m = fmaxf(m, __shfl_xor(m, 16));
    m = fmaxf(m, __shfl_xor(m, 32));
    float l = 0.f;
    #pragma unroll
    for (int f = 0; f < 14; ++f)
        #pragma unroll
        for (int r = 0; r < 4; ++r) {
            pex[f][r] = ex2(pex[f][r] - m);
            l += pex[f][r];
        }
    l += __shfl_xor(l, 16);
    l += __shfl_xor(l, 32);

    f32x4 of0 = {0.f, 0.f, 0.f, 0.f}, of1 = {0.f, 0.f, 0.f, 0.f};
    const int sbase = (g & 1) * 32 + c;
    #pragma unroll
    for (int kk = 0; kk < 7; ++kk) {
        uint32_t pk0[2], pk1[2];
        pk0[0] = cvtpk(pex[2 * kk][0], pex[2 * kk][1]);
        pk0[1] = cvtpk(pex[2 * kk][2], pex[2 * kk][3]);
        pk1[0] = cvtpk(pex[2 * kk + 1][0], pex[2 * kk + 1][1]);
        pk1[1] = cvtpk(pex[2 * kk + 1][2], pex[2 * kk + 1][3]);
        frag8 pb;
        #pragma unroll
        for (int tt = 0; tt < 4; ++tt) {
            const int srcLane = sbase + ((tt >> 1) << 4);
            const uint32_t v0 = __shfl(pk0[tt & 1], srcLane);
            const uint32_t v1 = __shfl(pk1[tt & 1], srcLane);
            pb.u[tt] = (g >= 2) ? v1 : v0;
        }
        frag8 va0, va1;
        va0.s = *reinterpret_cast<const short8*>(&Vt[c * VROWE + kk * 32 + g * 8]);
        va1.s = *reinterpret_cast<const short8*>(&Vt[(16 + c) * VROWE + kk * 32 + g * 8]);
        of0 = __builtin_amdgcn_mfma_f32_16x16x32_bf16(va0.s, pb.s, of0, 0, 0, 0);
        of1 = __builtin_amdgcn_mfma_f32_16x16x32_bf16(va1.s, pb.s, of1, 0, 0, 0);
    }

    const float invl = 1.f / l;
    uint32_t* dst = reinterpret_cast<uint32_t*>(attn + (rowbase + pixq) * DIMC + h * HD);
    dst[2 * g + 0] = cvtpk(of0[0] * invl, of0[1] * invl);
    dst[2 * g + 1] = cvtpk(of0[2] * invl, of0[3] * invl);
    dst[8 + 2 * g + 0] = cvtpk(of1[0] * invl, of1[1] * invl);
    dst[8 + 2 * g + 1] = cvtpk(of1[2] * invl, of1[3] * invl);
}

// ---------------- flash body (r13 v6 logic, smem passed in)
static __device__ __forceinline__
void flash_body(uint8_t* smem, int bid, const uint16_t* __restrict__ qkv,
                uint16_t* __restrict__ po, float2* __restrict__ pml)
{
    uint16_t (*Ks)[TK * ROWE]  = (uint16_t (*)[TK * ROWE])smem;          // 10240 B
    uint16_t (*Vt)[32 * VSTR]  = (uint16_t (*)[32 * VSTR])(smem + 10240); // 9216 B

    const int tid = threadIdx.x;
    const int lane = tid & 63, wv = tid >> 6;
    const int c = lane & 15, g = lane >> 4;
    const int split = bid & (KSPLIT - 1);
    const int qblk = (bid >> 2) % NQBLK;
    const int bh = bid / (KSPLIT * NQBLK);
    const int h = bh & (HEADS - 1);
    const int b = bh >> 3;
    const size_t rowbase = (size_t)b * NPIX;
    const int qbase = qblk * QB + wv * 32;
    const int q0 = qbase + c, q1 = qbase + 16 + c;

    frag8 qf0, qf1;
    qf0.s = *reinterpret_cast<const short8*>(qkv + (rowbase + q0) * C3 + 768 + h * HD + g * 8);
    qf1.s = *reinterpret_cast<const short8*>(qkv + (rowbase + q1) * C3 + 768 + h * HD + g * 8);

    float m0 = -1e30f, m1 = -1e30f, ls0 = 0.f, ls1 = 0.f;
    f32x4 oa00 = {0,0,0,0}, oa01 = {0,0,0,0};
    f32x4 oa10 = {0,0,0,0}, oa11 = {0,0,0,0};

    const int skk = tid >> 2, kd = (tid & 3) * 8;
    const int sgk = (skk & 15) | ((skk & 16) << 1) | ((skk & 32) >> 1);
    const int skv = tid >> 3, sdc = tid & 7;
    const int cp2 = 2 * (skv ^ ((sdc >> 1) << 3));

    uint4 KW; uint2 VA, VB;
#define STAGE_LOAD(T) do {                                                            \
    const size_t _tb = rowbase + split * KCHUNK + (T) * TK;                           \
    KW = *reinterpret_cast<const uint4*>(qkv + (_tb + sgk) * C3 + 1024 + h * HD + kd);\
    const uint16_t* _vp = qkv + (_tb + skv) * C3 + 1280 + h * HD + sdc * 4;           \
    VA = *reinterpret_cast<const uint2*>(_vp);                                        \
    VB = *reinterpret_cast<const uint2*>(_vp + 32 * C3); } while (0)

#define STAGE_WRITE(BUF) do {                                                         \
    *reinterpret_cast<uint4*>(&Ks[BUF][skk * ROWE + kd]) = KW;                        \
    const uint32_t _pa[4] = {VA.x & 0xffffu, VA.x >> 16, VA.y & 0xffffu, VA.y >> 16}; \
    const uint32_t _pb[4] = {VB.x & 0xffffu, VB.x >> 16, VB.y & 0xffffu, VB.y >> 16}; \
    _Pragma("unroll")                                                                 \
    for (int _i = 0; _i < 4; ++_i)                                                    \
        *reinterpret_cast<uint32_t*>(&Vt[BUF][(sdc * 4 + _i) * VSTR + cp2]) =         \
            _pa[_i] | (_pb[_i] << 16); } while (0)

    STAGE_LOAD(0);
    STAGE_WRITE(0);

    const int x0 = (c >> 3) << 3;
    const int x1 = 16 + x0;

    for (int t = 0; t < NTILES; ++t) {
        __syncthreads();

        const bool more = (t + 1 < NTILES);
        if (more) STAGE_LOAD(t + 1);

        const int cur = t & 1;
        frag8 ka0, ka1, ka2, ka3;
        ka0.s = *reinterpret_cast<const short8*>(&Ks[cur][c * ROWE + g * 8]);
        ka1.s = *reinterpret_cast<const short8*>(&Ks[cur][(16 + c) * ROWE + g * 8]);
        ka2.s = *reinterpret_cast<const short8*>(&Ks[cur][(32 + c) * ROWE + g * 8]);
        ka3.s = *reinterpret_cast<const short8*>(&Ks[cur][(48 + c) * ROWE + g * 8]);
        f32x4 sc0[4], sc1[4];
        #pragma unroll
        for (int kf = 0; kf < 4; ++kf) {
            sc0[kf] = (f32x4){0,0,0,0};
            sc1[kf] = (f32x4){0,0,0,0};
        }
        __builtin_amdgcn_s_setprio(1);
        sc0[0] = __builtin_amdgcn_mfma_f32_16x16x32_bf16(ka0.s, qf0.s, sc0[0], 0, 0, 0);
        sc0[1] = __builtin_amdgcn_mfma_f32_16x16x32_bf16(ka1.s, qf0.s, sc0[1], 0, 0, 0);
        sc0[2] = __builtin_amdgcn_mfma_f32_16x16x32_bf16(ka2.s, qf0.s, sc0[2], 0, 0, 0);
        sc0[3] = __builtin_amdgcn_mfma_f32_16x16x32_bf16(ka3.s, qf0.s, sc0[3], 0, 0, 0);
        sc1[0] = __builtin_amdgcn_mfma_f32_16x16x32_bf16(ka0.s, qf1.s, sc1[0], 0, 0, 0);
        sc1[1] = __builtin_amdgcn_mfma_f32_16x16x32_bf16(ka1.s, qf1.s, sc1[1], 0, 0, 0);
        sc1[2] = __builtin_amdgcn_mfma_f32_16x16x32_bf16(ka2.s, qf1.s, sc1[2], 0, 0, 0);
        sc1[3] = __builtin_amdgcn_mfma_f32_16x16x32_bf16(ka3.s, qf1.s, sc1[3], 0, 0, 0);
        __builtin_amdgcn_s_setprio(0);

        float t0 = sc0[0][0], t1 = sc1[0][0];
        #pragma unroll
        for (int kf = 0; kf < 4; ++kf)
            #pragma unroll
            for (int r = 0; r < 4; ++r) {
                t0 = fmaxf(t0, sc0[kf][r]);
                t1 = fmaxf(t1, sc1[kf][r]);
            }
        t0 = fmaxf(t0, __shfl_xor(t0, 16)); t0 = fmaxf(t0, __shfl_xor(t0, 32));
        t1 = fmaxf(t1, __shfl_xor(t1, 16)); t1 = fmaxf(t1, __shfl_xor(t1, 32));

        const int ok = (t0 - m0 <= 11.54f) && (t1 - m1 <= 11.54f);
        if (!__all(ok)) {
            const float nm0 = fmaxf(m0, t0), nm1 = fmaxf(m1, t1);
            const float c0 = ex2(m0 - nm0), c1 = ex2(m1 - nm1);
            ls0 *= c0; ls1 *= c1;
            oa00 *= c0; oa01 *= c0; oa10 *= c1; oa11 *= c1;
            m0 = nm0; m1 = nm1;
        }

        #pragma unroll
        for (int kf = 0; kf < 4; ++kf)
            #pragma unroll
            for (int r = 0; r < 4; ++r) {
                sc0[kf][r] = ex2(sc0[kf][r] - m0); ls0 += sc0[kf][r];
                sc1[kf][r] = ex2(sc1[kf][r] - m1); ls1 += sc1[kf][r];
            }

        #pragma unroll
        for (int kk = 0; kk < 2; ++kk) {
            frag8 pb0, pb1;
            #pragma unroll
            for (int tt = 0; tt < 4; ++tt) {
                pb0.u[tt] = cvtpk(sc0[2 * kk][tt], sc0[2 * kk + 1][tt]);
                pb1.u[tt] = cvtpk(sc1[2 * kk][tt], sc1[2 * kk + 1][tt]);
            }
            const int p0 = 16 * kk + 4 * g;
            frag8 va0, va1;
            va0.s = *reinterpret_cast<const short8*>(&Vt[cur][c * VSTR + 2 * (p0 ^ x0)]);
            va1.s = *reinterpret_cast<const short8*>(&Vt[cur][(16 + c) * VSTR + 2 * (p0 ^ x1)]);
            __builtin_amdgcn_s_setprio(1);
            oa00 = __builtin_amdgcn_mfma_f32_16x16x32_bf16(va0.s, pb0.s, oa00, 0, 0, 0);
            oa01 = __builtin_amdgcn_mfma_f32_16x16x32_bf16(va1.s, pb0.s, oa01, 0, 0, 0);
            oa10 = __builtin_amdgcn_mfma_f32_16x16x32_bf16(va0.s, pb1.s, oa10, 0, 0, 0);
            oa11 = __builtin_amdgcn_mfma_f32_16x16x32_bf16(va1.s, pb1.s, oa11, 0, 0, 0);
            __builtin_amdgcn_s_setprio(0);
        }

        if (more) STAGE_WRITE(cur ^ 1);
    }

    ls0 += __shfl_xor(ls0, 16); ls0 += __shfl_xor(ls0, 32);
    ls1 += __shfl_xor(ls1, 16); ls1 += __shfl_xor(ls1, 32);

    const float i0 = 1.f / ls0, i1 = 1.f / ls1;
    const size_t item0 = ((size_t)split * 16 + bh) * NPIX + q0;
    const size_t item1 = ((size_t)split * 16 + bh) * NPIX + q1;
    uint32_t* d0 = reinterpret_cast<uint32_t*>(po + item0 * HD);
    d0[2 * g + 0] = cvtpk(oa00[0] * i0, oa00[1] * i0);
    d0[2 * g + 1] = cvtpk(oa00[2] * i0, oa00[3] * i0);
    d0[8 + 2 * g + 0] = cvtpk(oa01[0] * i0, oa01[1] * i0);
    d0[8 + 2 * g + 1] = cvtpk(oa01[2] * i0, oa01[3] * i0);
    uint32_t* d1 = reinterpret_cast<uint32_t*>(po + item1 * HD);
    d1[2 * g + 0] = cvtpk(oa10[0] * i1, oa10[1] * i1);
    d1[2 * g + 1] = cvtpk(oa10[2] * i1, oa10[3] * i1);
    d1[8 + 2 * g + 0] = cvtpk(oa11[0] * i1, oa11[1] * i1);
    d1[8 + 2 * g + 1] = cvtpk(oa11[2] * i1, oa11[3] * i1);
    if (g == 0) {
        pml[item0] = make_float2(m0, ls0);
        pml[item1] = make_float2(m1, ls1);
    }
#undef STAGE_LOAD
#undef STAGE_WRITE
}

// ---------------- Fused attention dispatch: flash blocks first (long pole),
// na blocks fill. Independent work, disjoint outputs, shared LDS arena.
__global__ __launch_bounds__(256)
void attn_fused(const uint16_t* __restrict__ qkv, const float* __restrict__ rpb,
                uint16_t* __restrict__ attn, uint16_t* __restrict__ po,
                float2* __restrict__ pml)
{
    __shared__ __align__(16) uint8_t smem[33456];   // max(na 33444, flash 19456)
    const int bid = blockIdx.x;
    if (bid < NFLASH)
        flash_body(smem, bid, qkv, po, pml);
    else
        na_body(smem, bid - NFLASH, qkv, rpb, attn);
}

// ---------------- Combine split-K partials -> attn[:, 256:512) bf16 (log2 m)
__global__ __launch_bounds__(256)
void self_attn_combine(const uint16_t* __restrict__ po, const float2* __restrict__ pml,
                       uint16_t* __restrict__ attn)
{
    const int idx = blockIdx.x * 256 + threadIdx.x;
    const int d = idx & (HD - 1);
    const int q = (idx >> 5) % NPIX;
    const int bh = idx / (HD * NPIX);
    const int h = bh & (HEADS - 1);
    const int b = bh >> 3;

    float2 ml[KSPLIT];
    float M = -1e30f;
    #pragma unroll
    for (int s = 0; s < KSPLIT; ++s) {
        ml[s] = pml[((size_t)s * 16 + bh) * NPIX + q];
        M = fmaxf(M, ml[s].x);
    }
    float num = 0.f, den = 0.f;
    #pragma unroll
    for (int s = 0; s < KSPLIT; ++s) {
        const float w = ex2(ml[s].x - M) * ml[s].y;
        const float o = bf2f((uint32_t)po[(((size_t)s * 16 + bh) * NPIX + q) * HD + d]);
        num = fmaf(w, o, num);
        den += w;
    }
    attn[((size_t)b * NPIX + q) * DIMC + 256 + h * HD + d] = f2bf(num / den);
}

extern "C" void kernel_launch(void* const* d_in, const int* in_sizes, int n_in,
                              void* d_out, int out_size, void* d_ws, size_t ws_size,
                              hipStream_t stream)
{
    const float* x     = (const float*)d_in[0];
    const float* Wqkv  = (const float*)d_in[1];
    const float* bqkv  = (const float*)d_in[2];
    const float* rpb   = (const float*)d_in[3];
    const float* Wproj = (const float*)d_in[4];
    const float* bproj = (const float*)d_in[5];

    uint16_t* qkv  = (uint16_t*)d_ws;                           // 14.2 MB
    uint16_t* attn = qkv + (size_t)ROWS * C3;                   //  4.7 MB [ROWS][DIMC]
    uint16_t* wqt  = attn + (size_t)ROWS * DIMC;                //  1.6 MB
    uint16_t* wpt  = wqt + (size_t)C3 * DIMC;                   //  0.5 MB
    uint16_t* po   = wpt + (size_t)DIMC * DIMC;                 //  9.4 MB
    float2*   pml  = (float2*)(po + (size_t)KSPLIT * 16 * NPIX * HD); // 1.2 MB

    const dim3 blk(256);
    prep_weights<<<dim3(1024), blk, 0, stream>>>(Wqkv, Wproj, wqt, wpt);
    gemm_mfma<true, false, true><<<dim3(C3 / 128, ROWS / 128), blk, 0, stream>>>(
        x, wqt, bqkv, qkv, ROWS, C3, DIMC);
    attn_fused<<<dim3(NFLASH + BB * HEADS * 36), blk, 0, stream>>>(qkv, rpb, attn, po, pml);
    self_attn_combine<<<dim3((16 * NPIX * HD) / 256), blk, 0, stream>>>(po, pml, attn);
    gemm_mfma<false, true, false><<<dim3(DIMC / 128, ROWS / 128), blk, 0, stream>>>(
        attn, wpt, bproj, d_out, ROWS, DIMC, DIMC);
}